// Round 12
// baseline (285.429 us; speedup 1.0000x reference)
//
#include <hip/hip_runtime.h>

#define N_NODES 20000
#define N_EDGES 160000
#define CIN     2000
#define N1      500
#define N2      250
#define NH      34     // heads: 1 + 1 + 16 + 16
#define NHP     64

typedef __attribute__((ext_vector_type(4))) float f32x4;
typedef __attribute__((ext_vector_type(8))) __bf16 bf16x8;
typedef __attribute__((ext_vector_type(8))) unsigned short ushort8;

typedef const __attribute__((address_space(1))) void* as1cv;
typedef __attribute__((address_space(3))) void* as3v;

__device__ __forceinline__ unsigned short f2bf(float f) {
    unsigned int u = __builtin_bit_cast(unsigned int, f);
    u += 0x7FFFu + ((u >> 16) & 1u);   // RNE
    return (unsigned short)(u >> 16);
}

__device__ __forceinline__ ushort8 pack8(float4 a, float4 b) {
    ushort8 r;
    r[0] = f2bf(a.x); r[1] = f2bf(a.y); r[2] = f2bf(a.z); r[3] = f2bf(a.w);
    r[4] = f2bf(b.x); r[5] = f2bf(b.y); r[6] = f2bf(b.z); r[7] = f2bf(b.w);
    return r;
}

// == K1: k_count (625) || V = Wh@W2 (128) || W1 transpose -> bf16 (1024) ==
__global__ __launch_bounds__(256) void k1(
    const int* __restrict__ ei, const float* __restrict__ ew,
    float* degsum, int* cnt,
    const float* __restrict__ W2,
    const float* __restrict__ Wmt, const float* __restrict__ Wst,
    const float* __restrict__ Wmz, const float* __restrict__ Wsz,
    float* __restrict__ V, unsigned short* __restrict__ Vb,
    const float* __restrict__ W1, unsigned short* __restrict__ W1T) {
    __shared__ float tile[32][33];
    const int B = blockIdx.x, t = threadIdx.x;
    if (B < 625) {                      // ---- k_count ----
        int e = B * 256 + t;
        if (e < N_EDGES) {
            int d = ei[N_EDGES + e];
            atomicAdd(&degsum[d], ew[e]);
            atomicAdd(&cnt[d], 1);
        }
        return;
    }
    if (B < 753) {                      // ---- V[o][n] = sum_j Wh[o][j] W2[j][n] ----
        float* wh = &tile[0][0];
        int b = B - 625;
        int o = b >> 1, half = b & 1;
        int n = half * 256 + t;
        if (o >= NH) {
            V[(size_t)o * 512 + n] = 0.f;
            Vb[(size_t)o * 512 + n] = 0;
            return;
        }
        const float* src; int row;
        if (o == 0)      { src = Wmt; row = 0; }
        else if (o == 1) { src = Wst; row = 0; }
        else if (o < 18) { src = Wmz; row = o - 2; }
        else             { src = Wsz; row = o - 18; }
        if (t < N2) wh[t] = src[(size_t)row * N2 + t];
        __syncthreads();
        float acc = 0.f;
        if (n < N1) {
            for (int j = 0; j < N2; ++j) acc += wh[j] * W2[(size_t)j * N1 + n];
        }
        float v = (n < N1) ? acc : 0.f;
        V[(size_t)o * 512 + n] = v;
        Vb[(size_t)o * 512 + n] = f2bf(v);
        return;
    }
    // ---- transpose W1 [500][2000] -> W1T bf16 [2048][512] ----
    int bb = B - 753;
    int jt = bb & 15, nt = bb >> 4;
    int c = t & 31, r = t >> 5;
#pragma unroll
    for (int i = 0; i < 4; ++i) {
        int j = jt * 32 + r + i * 8;
        int n = nt * 32 + c;
        tile[r + i * 8][c] = (j < N1 && n < CIN) ? W1[(size_t)j * CIN + n] : 0.f;
    }
    __syncthreads();
#pragma unroll
    for (int i = 0; i < 4; ++i) {
        int n = nt * 32 + r + i * 8;
        int j = jt * 32 + c;
        W1T[(size_t)n * 512 + j] = f2bf(tile[c][r + i * 8]);
    }
}

// == K2: scan+dinv (1) || ccdd (1) || MFMA gemm Wt = Vb @ W1T^T (16 blocks) ==
__global__ __launch_bounds__(256) void k2(
    const int* __restrict__ cnt, const float* __restrict__ degsum,
    float* __restrict__ dinv, int* __restrict__ rowPtr,
    const unsigned short* __restrict__ Vb, const unsigned short* __restrict__ W1T,
    unsigned short* __restrict__ Wtb,
    const float* __restrict__ V,
    const float* __restrict__ b1, const float* __restrict__ b2,
    const float* __restrict__ bmt, const float* __restrict__ bst,
    const float* __restrict__ bmz, const float* __restrict__ bsz,
    const float* __restrict__ Wmt, const float* __restrict__ Wst,
    const float* __restrict__ Wmz, const float* __restrict__ Wsz,
    float* __restrict__ ccdd) {
    __shared__ alignas(16) unsigned short lA[128 * 32];
    __shared__ alignas(16) unsigned short lB[128 * 32];
    __shared__ int partial[1024];
    const int B = blockIdx.x, t = threadIdx.x;
    if (B == 0) {                       // ---- two-pass single-block scan + dinv ----
        int base = t * 80;
        int s = 0;
        for (int i = 0; i < 80; ++i) {
            int idx = base + i;
            if (idx < N_NODES) { s += cnt[idx]; dinv[idx] = rsqrtf(1.0f + degsum[idx]); }
        }
        partial[t] = s;
        __syncthreads();
        for (int off = 1; off < 256; off <<= 1) {
            int x = (t >= off) ? partial[t - off] : 0;
            __syncthreads();
            partial[t] += x;
            __syncthreads();
        }
        int run = (t == 0) ? 0 : partial[t - 1];
        for (int i = 0; i < 80; ++i) {
            int idx = base + i;
            if (idx < N_NODES) { rowPtr[idx] = run; run += cnt[idx]; }
        }
        if (t == 255) rowPtr[N_NODES] = partial[255];
        return;
    }
    if (B == 1) {                       // ---- ccdd: cc = V@b1, dd = Wh@b2 + bh ----
        int w = t >> 6, lane = t & 63;
        for (int o = w; o < NH; o += 4) {
            float cc = 0.f;
            for (int n = lane; n < N1; n += 64) cc += V[(size_t)o * 512 + n] * b1[n];
            const float* src; int row; float bias;
            if (o == 0)      { src = Wmt; row = 0;      bias = bmt[0]; }
            else if (o == 1) { src = Wst; row = 0;      bias = bst[0]; }
            else if (o < 18) { src = Wmz; row = o - 2;  bias = bmz[o - 2]; }
            else             { src = Wsz; row = o - 18; bias = bsz[o - 18]; }
            float dd = 0.f;
            for (int j = lane; j < N2; j += 64) dd += src[(size_t)row * N2 + j] * b2[j];
#pragma unroll
            for (int off = 32; off; off >>= 1) {
                cc += __shfl_down(cc, off);
                dd += __shfl_down(dd, off);
            }
            if (lane == 0) { ccdd[o] = cc; ccdd[NHP + o] = dd + bias; }
        }
        if (t >= NH && t < NHP) { ccdd[t] = 0.f; ccdd[NHP + t] = 0.f; }
        return;
    }
    // ---- MFMA gemm: Wtb[64][2048] = Vb[64][512] @ W1T[2048][512]^T ----
    {
        const int w = t >> 6, lane = t & 63;
        const int bn0 = (B - 2) * 128;
        const int M = 64;
        const int wr = w >> 1, wc = w & 1;
        const int lr = lane & 15, lk = (lane >> 4) * 8;
        f32x4 acc[4][4];
#pragma unroll
        for (int i = 0; i < 4; i++)
#pragma unroll
            for (int j = 0; j < 4; j++) acc[i][j] = (f32x4){0.f, 0.f, 0.f, 0.f};
        for (int kt = 0; kt < 16; ++kt) {
            const int kb = kt * 32;
#pragma unroll
            for (int i = 0; i < 2; i++) {
                int c0 = i * 256 + w * 64;
                int c  = c0 + lane;
                int rr = c >> 2, kg = c & 3;
                int grow = rr < M ? rr : M - 1;
                const unsigned short* gp = Vb + (size_t)grow * 512 + kb + kg * 8;
                __builtin_amdgcn_global_load_lds((as1cv)gp, (as3v)(lA + (size_t)c0 * 8), 16, 0, 0);
            }
#pragma unroll
            for (int i = 0; i < 2; i++) {
                int c0 = i * 256 + w * 64;
                int c  = c0 + lane;
                int rr = c >> 2, kg = c & 3;
                const unsigned short* gp = W1T + (size_t)(bn0 + rr) * 512 + kb + kg * 8;
                __builtin_amdgcn_global_load_lds((as1cv)gp, (as3v)(lB + (size_t)c0 * 8), 16, 0, 0);
            }
            __syncthreads();
            ushort8 af[4], bfr[4];
#pragma unroll
            for (int m = 0; m < 4; m++)
                af[m] = *reinterpret_cast<const ushort8*>(&lA[(wr * 64 + m * 16 + lr) * 32 + lk]);
#pragma unroll
            for (int n = 0; n < 4; n++)
                bfr[n] = *reinterpret_cast<const ushort8*>(&lB[(wc * 64 + n * 16 + lr) * 32 + lk]);
#pragma unroll
            for (int m = 0; m < 4; m++)
#pragma unroll
                for (int n = 0; n < 4; n++)
                    acc[m][n] = __builtin_amdgcn_mfma_f32_16x16x32_bf16(
                        __builtin_bit_cast(bf16x8, af[m]), __builtin_bit_cast(bf16x8, bfr[n]),
                        acc[m][n], 0, 0, 0);
            __syncthreads();
        }
        const int crow0 = wr * 64 + (lane >> 4) * 4;
        const int ccol0 = bn0 + wc * 64 + lr;
#pragma unroll
        for (int m = 0; m < 4; m++)
#pragma unroll
            for (int n = 0; n < 4; n++)
#pragma unroll
                for (int rg = 0; rg < 4; rg++) {
                    int row = crow0 + m * 16 + rg;
                    if (row < M)
                        Wtb[(size_t)row * 2048 + ccol0 + n * 16] = f2bf(acc[m][n][rg]);
                }
    }
}

// ============ K3g: gemm_T only (626 blocks) — idempotent, replicated for timing ============
__global__ __launch_bounds__(256) void k3g(
    const float* __restrict__ X, const unsigned short* __restrict__ Wtb,
    float* __restrict__ Tpart) {
    __shared__ alignas(16) unsigned short lA[64 * 64];
    __shared__ alignas(16) unsigned short lB[64 * 64];
    const int B = blockIdx.x, t = threadIdx.x;
    const int w = t >> 6, lane = t & 63;
    const int kp = B & 1;
    const int bm0 = (B >> 1) * 64;
    const int kbase = kp * 1024;
    const int lr = lane & 15, lkb = (lane >> 4) * 16;

    const int c0 = t, c1 = t + 256;
    const int ar0 = c0 >> 3, ac0 = (c0 & 7) * 8;
    const int ar1 = c1 >> 3, ac1 = (c1 & 7) * 8;
    int gr0 = bm0 + ar0; if (gr0 >= N_NODES) gr0 = N_NODES - 1;
    int gr1 = bm0 + ar1; if (gr1 >= N_NODES) gr1 = N_NODES - 1;
    const float* pA0 = X + (size_t)gr0 * CIN + kbase + ac0;
    const float* pA1 = X + (size_t)gr1 * CIN + kbase + ac1;
    const unsigned short* pB0 = Wtb + ar0 * 2048 + kbase + ac0;
    const unsigned short* pB1 = Wtb + ar1 * 2048 + kbase + ac1;
    char* const LA = (char*)lA;
    char* const LB = (char*)lB;
    char* const wA0 = LA + ((ar0 * 128 + ac0 * 2) ^ ((ar0 & 7) << 4));
    char* const wA1 = LA + ((ar1 * 128 + ac1 * 2) ^ ((ar1 & 7) << 4));
    char* const wB0 = LB + ((ar0 * 128 + ac0 * 2) ^ ((ar0 & 7) << 4));
    char* const wB1 = LB + ((ar1 * 128 + ac1 * 2) ^ ((ar1 & 7) << 4));

    int aoff[4][2], boff[2];
#pragma unroll
    for (int m = 0; m < 4; ++m)
#pragma unroll
        for (int k = 0; k < 2; ++k)
            aoff[m][k] = (((m * 16 + lr) * 128 + k * 64 + lkb) ^ ((lr & 7) << 4));
#pragma unroll
    for (int k = 0; k < 2; ++k)
        boff[k] = (((w * 16 + lr) * 128 + k * 64 + lkb) ^ ((lr & 7) << 4));

    f32x4 acc[4];
#pragma unroll
    for (int m = 0; m < 4; ++m) acc[m] = (f32x4){0.f, 0.f, 0.f, 0.f};

    float4 a00, a01, a10, a11;
    ushort8 bv0, bv1;
    const float4 z4 = make_float4(0.f, 0.f, 0.f, 0.f);

#define STAGE_LOAD(S)                                                              \
    {                                                                              \
        bool v0 = (kbase + ac0 + (S) * 64) < CIN;                                  \
        bool v1 = (kbase + ac1 + (S) * 64) < CIN;                                  \
        const float4* q0 = (const float4*)(v0 ? pA0 + (S) * 64 : (const float*)X); \
        const float4* q1 = (const float4*)(v1 ? pA1 + (S) * 64 : (const float*)X); \
        a00 = q0[0]; a01 = q0[1];                                                  \
        a10 = q1[0]; a11 = q1[1];                                                  \
        if (!v0) { a00 = z4; a01 = z4; }                                           \
        if (!v1) { a10 = z4; a11 = z4; }                                           \
        bv0 = *(const ushort8*)(pB0 + (S) * 64);                                   \
        bv1 = *(const ushort8*)(pB1 + (S) * 64);                                   \
    }

    STAGE_LOAD(0)
    for (int s = 0; s < 16; ++s) {
        __syncthreads();
        *(ushort8*)wA0 = pack8(a00, a01);
        *(ushort8*)wA1 = pack8(a10, a11);
        *(ushort8*)wB0 = bv0;
        *(ushort8*)wB1 = bv1;
        __syncthreads();
        if (s < 15) STAGE_LOAD(s + 1)
#pragma unroll
        for (int k = 0; k < 2; ++k) {
            ushort8 bf = *(const ushort8*)(LB + boff[k]);
#pragma unroll
            for (int m = 0; m < 4; ++m) {
                ushort8 af = *(const ushort8*)(LA + aoff[m][k]);
                acc[m] = __builtin_amdgcn_mfma_f32_16x16x32_bf16(
                    __builtin_bit_cast(bf16x8, af), __builtin_bit_cast(bf16x8, bf),
                    acc[m], 0, 0, 0);
            }
        }
    }
#undef STAGE_LOAD
    float* Tp = Tpart + (size_t)kp * N_NODES * NHP;
    const int col = w * 16 + lr;
    const int rb = bm0 + (lane >> 4) * 4;
#pragma unroll
    for (int m = 0; m < 4; ++m)
#pragma unroll
        for (int rg = 0; rg < 4; ++rg) {
            int row = rb + m * 16 + rg;
            if (row < N_NODES) Tp[(size_t)row * NHP + col] = acc[m][rg];
        }
}

// ============ K3f: k_fill only (625 blocks) ============
__global__ __launch_bounds__(256) void k3f(
    const int* __restrict__ ei, const float* __restrict__ ew,
    const float* __restrict__ dinv, const int* __restrict__ rowPtr,
    int* cursor, int* __restrict__ colA, float* __restrict__ valA) {
    int e = blockIdx.x * 256 + threadIdx.x;
    if (e < N_EDGES) {
        int s = ei[e], d = ei[N_EDGES + e];
        int p = atomicAdd(&cursor[d], 1);
        int j = rowPtr[d] + p;
        colA[j] = s;
        valA[j] = dinv[s] * ew[e] * dinv[d];
    }
}

// ================= K4: agg_a with fused split-K reduce =================
__global__ __launch_bounds__(256) void agg_a(
    const float* __restrict__ Tp, const int* __restrict__ rowPtr,
    const int* __restrict__ colA, const float* __restrict__ valA,
    const float* __restrict__ dinv, float* __restrict__ U) {
    const float* __restrict__ T1 = Tp + (size_t)N_NODES * NHP;
    int wid = blockIdx.x * 4 + (threadIdx.x >> 6);
    int lane = threadIdx.x & 63;
    if (wid >= N_NODES) return;
    int d = wid;
    float dv = dinv[d];
    float acc = dv * dv * (Tp[(size_t)d * NHP + lane] + T1[(size_t)d * NHP + lane]);
    int e0 = rowPtr[d], e1 = rowPtr[d + 1];
    int e = e0;
    for (; e + 4 <= e1; e += 4) {
        int s0 = colA[e], s1 = colA[e + 1], s2 = colA[e + 2], s3 = colA[e + 3];
        float w0 = valA[e], w1 = valA[e + 1], w2 = valA[e + 2], w3 = valA[e + 3];
        float t0 = Tp[(size_t)s0 * NHP + lane] + T1[(size_t)s0 * NHP + lane];
        float t1 = Tp[(size_t)s1 * NHP + lane] + T1[(size_t)s1 * NHP + lane];
        float t2 = Tp[(size_t)s2 * NHP + lane] + T1[(size_t)s2 * NHP + lane];
        float t3 = Tp[(size_t)s3 * NHP + lane] + T1[(size_t)s3 * NHP + lane];
        acc += w0 * t0 + w1 * t1 + w2 * t2 + w3 * t3;
    }
    for (; e < e1; ++e) {
        int s = colA[e];
        acc += valA[e] * (Tp[(size_t)s * NHP + lane] + T1[(size_t)s * NHP + lane]);
    }
    U[(size_t)d * NHP + lane] = acc;
}

// ============ K5: agg_b: out = act( A_hat @ U + rowsum*cc + dd ) ============
__global__ __launch_bounds__(256) void agg_b(
    const float* __restrict__ U, const int* __restrict__ rowPtr,
    const int* __restrict__ colA, const float* __restrict__ valA,
    const float* __restrict__ dinv, const float* __restrict__ ccdd,
    float* __restrict__ out) {
    int wid = blockIdx.x * 4 + (threadIdx.x >> 6);
    int lane = threadIdx.x & 63;
    if (wid >= N_NODES) return;
    int d = wid;
    float dv = dinv[d], self = dv * dv;
    float acc = self * U[(size_t)d * NHP + lane];
    float r = self;
    int e0 = rowPtr[d], e1 = rowPtr[d + 1];
    int e = e0;
    for (; e + 4 <= e1; e += 4) {
        int s0 = colA[e], s1 = colA[e + 1], s2 = colA[e + 2], s3 = colA[e + 3];
        float w0 = valA[e], w1 = valA[e + 1], w2 = valA[e + 2], w3 = valA[e + 3];
        float t0 = U[(size_t)s0 * NHP + lane];
        float t1 = U[(size_t)s1 * NHP + lane];
        float t2 = U[(size_t)s2 * NHP + lane];
        float t3 = U[(size_t)s3 * NHP + lane];
        acc += w0 * t0 + w1 * t1 + w2 * t2 + w3 * t3;
        r += w0 + w1 + w2 + w3;
    }
    for (; e < e1; ++e) {
        int s = colA[e];
        float wv = valA[e];
        acc += wv * U[(size_t)s * NHP + lane];
        r += wv;
    }
    if (lane < NH) {
        float v = acc + r * ccdd[lane] + ccdd[NHP + lane];
        if (lane < 2 || lane >= 18)
            v = fmaxf(v, 0.f) + log1pf(expf(-fabsf(v)));
        size_t oidx;
        if (lane == 0)      oidx = (size_t)d;
        else if (lane == 1) oidx = (size_t)N_NODES + d;
        else if (lane < 18) oidx = (size_t)2 * N_NODES + (size_t)d * 16 + (lane - 2);
        else                oidx = (size_t)18 * N_NODES + (size_t)d * 16 + (lane - 18);
        out[oidx] = v;
    }
}

extern "C" void kernel_launch(void* const* d_in, const int* in_sizes, int n_in,
                              void* d_out, int out_size, void* d_ws, size_t ws_size,
                              hipStream_t stream) {
    const float* X   = (const float*)d_in[0];
    const int*   EI  = (const int*)d_in[1];
    const float* EW  = (const float*)d_in[2];
    const float* W1  = (const float*)d_in[3];
    const float* b1  = (const float*)d_in[4];
    const float* W2  = (const float*)d_in[5];
    const float* b2  = (const float*)d_in[6];
    const float* Wmt = (const float*)d_in[7];
    const float* bmt = (const float*)d_in[8];
    const float* Wst = (const float*)d_in[9];
    const float* bst = (const float*)d_in[10];
    const float* Wmz = (const float*)d_in[11];
    const float* bmz = (const float*)d_in[12];
    const float* Wsz = (const float*)d_in[13];
    const float* bsz = (const float*)d_in[14];
    float* out = (float*)d_out;

    char* ws = (char*)d_ws;
    size_t off = 0;
    auto alloc = [&](size_t bytes) -> char* {
        char* p = ws + off;
        off += (bytes + 255) & ~(size_t)255;
        return p;
    };
    float*          V    = (float*)alloc((size_t)NHP * 512 * 4);
    unsigned short* Vb   = (unsigned short*)alloc((size_t)NHP * 512 * 2);
    unsigned short* W1T  = (unsigned short*)alloc((size_t)2048 * 512 * 2);
    unsigned short* Wtb  = (unsigned short*)alloc((size_t)NHP * 2048 * 2);
    float*          ccdd = (float*)alloc(2 * NHP * 4);
    float*          Tp   = (float*)alloc((size_t)2 * N_NODES * NHP * 4);
    float*          U    = (float*)alloc((size_t)N_NODES * NHP * 4);
    float* degsum = (float*)alloc(N_NODES * 4);
    int*   cnt    = (int*)alloc(N_NODES * 4);
    int*   cursor = (int*)alloc(N_NODES * 4);
    float* dinv   = (float*)alloc(N_NODES * 4);
    int*   rowPtr = (int*)alloc((N_NODES + 1) * 4);
    int*   colA   = (int*)alloc(N_EDGES * 4);
    float* valA   = (float*)alloc(N_EDGES * 4);
    if (off > ws_size) return;   // loud failure: d_out stays poisoned

    // zero {degsum, cnt, cursor} in one async memset (contiguous span)
    size_t zspan = (size_t)((char*)(cursor + N_NODES) - (char*)degsum);
    hipMemsetAsync(degsum, 0, zspan, stream);

    k1<<<625 + 128 + 1024, 256, 0, stream>>>(EI, EW, degsum, cnt,
                                             W2, Wmt, Wst, Wmz, Wsz, V, Vb, W1, W1T);
    k2<<<2 + 16, 256, 0, stream>>>(cnt, degsum, dinv, rowPtr, Vb, W1T, Wtb, V,
                                   b1, b2, bmt, bst, bmz, bsz, Wmt, Wst, Wmz, Wsz, ccdd);
    // MEASUREMENT: gemm_T replicated 5x (idempotent). gemm_T = (total - ~158)/4.
    for (int rep = 0; rep < 5; ++rep)
        k3g<<<626, 256, 0, stream>>>(X, Wtb, Tp);
    k3f<<<625, 256, 0, stream>>>(EI, EW, dinv, rowPtr, cursor, colA, valA);
    agg_a<<<(N_NODES + 3) / 4, 256, 0, stream>>>(Tp, rowPtr, colA, valA, dinv, U);
    agg_b<<<(N_NODES + 3) / 4, 256, 0, stream>>>(U, rowPtr, colA, valA, dinv, ccdd, out);
}

// Round 13
// 124.406 us; speedup vs baseline: 2.2943x; 2.2943x over previous
//
#include <hip/hip_runtime.h>

#define N_NODES 20000
#define N_EDGES 160000
#define CIN     2000
#define N1      500
#define N2      250
#define NH      34     // heads: 1 + 1 + 16 + 16
#define NHP     64

typedef __attribute__((ext_vector_type(4))) float f32x4;
typedef __attribute__((ext_vector_type(8))) __bf16 bf16x8;
typedef __attribute__((ext_vector_type(8))) unsigned short ushort8;

typedef const __attribute__((address_space(1))) void* as1cv;
typedef __attribute__((address_space(3))) void* as3v;

__device__ __forceinline__ unsigned short f2bf(float f) {
    unsigned int u = __builtin_bit_cast(unsigned int, f);
    u += 0x7FFFu + ((u >> 16) & 1u);   // RNE
    return (unsigned short)(u >> 16);
}

__device__ __forceinline__ ushort8 pack8(float4 a, float4 b) {
    ushort8 r;
    r[0] = f2bf(a.x); r[1] = f2bf(a.y); r[2] = f2bf(a.z); r[3] = f2bf(a.w);
    r[4] = f2bf(b.x); r[5] = f2bf(b.y); r[6] = f2bf(b.z); r[7] = f2bf(b.w);
    return r;
}

// == K1: k_count (625) || V = Wh@W2 (128) || W1 transpose -> bf16 (1024) ==
__global__ __launch_bounds__(256) void k1(
    const int* __restrict__ ei, const float* __restrict__ ew,
    float* degsum, int* cnt,
    const float* __restrict__ W2,
    const float* __restrict__ Wmt, const float* __restrict__ Wst,
    const float* __restrict__ Wmz, const float* __restrict__ Wsz,
    float* __restrict__ V, unsigned short* __restrict__ Vb,
    const float* __restrict__ W1, unsigned short* __restrict__ W1T) {
    __shared__ float tile[32][33];
    const int B = blockIdx.x, t = threadIdx.x;
    if (B < 625) {                      // ---- k_count ----
        int e = B * 256 + t;
        if (e < N_EDGES) {
            int d = ei[N_EDGES + e];
            atomicAdd(&degsum[d], ew[e]);
            atomicAdd(&cnt[d], 1);
        }
        return;
    }
    if (B < 753) {                      // ---- V[o][n] = sum_j Wh[o][j] W2[j][n] ----
        float* wh = &tile[0][0];
        int b = B - 625;
        int o = b >> 1, half = b & 1;
        int n = half * 256 + t;
        if (o >= NH) {
            V[(size_t)o * 512 + n] = 0.f;
            Vb[(size_t)o * 512 + n] = 0;
            return;
        }
        const float* src; int row;
        if (o == 0)      { src = Wmt; row = 0; }
        else if (o == 1) { src = Wst; row = 0; }
        else if (o < 18) { src = Wmz; row = o - 2; }
        else             { src = Wsz; row = o - 18; }
        if (t < N2) wh[t] = src[(size_t)row * N2 + t];
        __syncthreads();
        float acc = 0.f;
        if (n < N1) {
            for (int j = 0; j < N2; ++j) acc += wh[j] * W2[(size_t)j * N1 + n];
        }
        float v = (n < N1) ? acc : 0.f;
        V[(size_t)o * 512 + n] = v;
        Vb[(size_t)o * 512 + n] = f2bf(v);
        return;
    }
    // ---- transpose W1 [500][2000] -> W1T bf16 [2048][512] ----
    int bb = B - 753;
    int jt = bb & 15, nt = bb >> 4;
    int c = t & 31, r = t >> 5;
#pragma unroll
    for (int i = 0; i < 4; ++i) {
        int j = jt * 32 + r + i * 8;
        int n = nt * 32 + c;
        tile[r + i * 8][c] = (j < N1 && n < CIN) ? W1[(size_t)j * CIN + n] : 0.f;
    }
    __syncthreads();
#pragma unroll
    for (int i = 0; i < 4; ++i) {
        int n = nt * 32 + r + i * 8;
        int j = jt * 32 + c;
        W1T[(size_t)n * 512 + j] = f2bf(tile[c][r + i * 8]);
    }
}

// == K2: parallel scan+dinv (79) || ccdd (1) || MFMA gemm Wt = Vb @ W1T^T (16) ==
__global__ __launch_bounds__(256) void k2(
    const int* __restrict__ cnt, const float* __restrict__ degsum,
    float* __restrict__ dinv, int* __restrict__ rowPtr,
    const unsigned short* __restrict__ Vb, const unsigned short* __restrict__ W1T,
    unsigned short* __restrict__ Wtb,
    const float* __restrict__ V,
    const float* __restrict__ b1, const float* __restrict__ b2,
    const float* __restrict__ bmt, const float* __restrict__ bst,
    const float* __restrict__ bmz, const float* __restrict__ bsz,
    const float* __restrict__ Wmt, const float* __restrict__ Wst,
    const float* __restrict__ Wmz, const float* __restrict__ Wsz,
    float* __restrict__ ccdd) {
    __shared__ alignas(16) unsigned short lA[128 * 32];
    __shared__ alignas(16) unsigned short lB[128 * 32];
    __shared__ int sdata[256];
    const int B = blockIdx.x, t = threadIdx.x;
    if (B < 79) {                       // ---- scan chunk b: sync-free redundant prefix ----
        const int nbase = B * 256;
        // base = sum cnt[0..nbase) — coalesced, L2-hot, parallel across blocks
        int s = 0;
        for (int i = t; i < nbase; i += 256) s += cnt[i];
        sdata[t] = s;
        __syncthreads();
        for (int off = 128; off; off >>= 1) {
            if (t < off) sdata[t] += sdata[t + off];
            __syncthreads();
        }
        const int base = sdata[0];
        __syncthreads();
        // own chunk: coalesced load + dinv; 256-wide inclusive scan
        int idx = nbase + t;
        int v = 0;
        if (idx < N_NODES) {
            v = cnt[idx];
            dinv[idx] = rsqrtf(1.0f + degsum[idx]);
        }
        sdata[t] = v;
        __syncthreads();
        for (int off = 1; off < 256; off <<= 1) {
            int x = (t >= off) ? sdata[t - off] : 0;
            __syncthreads();
            sdata[t] += x;
            __syncthreads();
        }
        if (idx < N_NODES) rowPtr[idx] = base + sdata[t] - v;   // exclusive
        if (B == 78 && t == 255) rowPtr[N_NODES] = base + sdata[255];
        return;
    }
    if (B == 79) {                      // ---- ccdd: cc = V@b1, dd = Wh@b2 + bh ----
        int w = t >> 6, lane = t & 63;
        for (int o = w; o < NH; o += 4) {
            float cc = 0.f;
            for (int n = lane; n < N1; n += 64) cc += V[(size_t)o * 512 + n] * b1[n];
            const float* src; int row; float bias;
            if (o == 0)      { src = Wmt; row = 0;      bias = bmt[0]; }
            else if (o == 1) { src = Wst; row = 0;      bias = bst[0]; }
            else if (o < 18) { src = Wmz; row = o - 2;  bias = bmz[o - 2]; }
            else             { src = Wsz; row = o - 18; bias = bsz[o - 18]; }
            float dd = 0.f;
            for (int j = lane; j < N2; j += 64) dd += src[(size_t)row * N2 + j] * b2[j];
#pragma unroll
            for (int off = 32; off; off >>= 1) {
                cc += __shfl_down(cc, off);
                dd += __shfl_down(dd, off);
            }
            if (lane == 0) { ccdd[o] = cc; ccdd[NHP + o] = dd + bias; }
        }
        if (t >= NH && t < NHP) { ccdd[t] = 0.f; ccdd[NHP + t] = 0.f; }
        return;
    }
    // ---- MFMA gemm: Wtb[64][2048] = Vb[64][512] @ W1T[2048][512]^T ----
    {
        const int w = t >> 6, lane = t & 63;
        const int bn0 = (B - 80) * 128;
        const int M = 64;
        const int wr = w >> 1, wc = w & 1;
        const int lr = lane & 15, lk = (lane >> 4) * 8;
        f32x4 acc[4][4];
#pragma unroll
        for (int i = 0; i < 4; i++)
#pragma unroll
            for (int j = 0; j < 4; j++) acc[i][j] = (f32x4){0.f, 0.f, 0.f, 0.f};
        for (int kt = 0; kt < 16; ++kt) {
            const int kb = kt * 32;
#pragma unroll
            for (int i = 0; i < 2; i++) {
                int c0 = i * 256 + w * 64;
                int c  = c0 + lane;
                int rr = c >> 2, kg = c & 3;
                int grow = rr < M ? rr : M - 1;
                const unsigned short* gp = Vb + (size_t)grow * 512 + kb + kg * 8;
                __builtin_amdgcn_global_load_lds((as1cv)gp, (as3v)(lA + (size_t)c0 * 8), 16, 0, 0);
            }
#pragma unroll
            for (int i = 0; i < 2; i++) {
                int c0 = i * 256 + w * 64;
                int c  = c0 + lane;
                int rr = c >> 2, kg = c & 3;
                const unsigned short* gp = W1T + (size_t)(bn0 + rr) * 512 + kb + kg * 8;
                __builtin_amdgcn_global_load_lds((as1cv)gp, (as3v)(lB + (size_t)c0 * 8), 16, 0, 0);
            }
            __syncthreads();
            ushort8 af[4], bfr[4];
#pragma unroll
            for (int m = 0; m < 4; m++)
                af[m] = *reinterpret_cast<const ushort8*>(&lA[(wr * 64 + m * 16 + lr) * 32 + lk]);
#pragma unroll
            for (int n = 0; n < 4; n++)
                bfr[n] = *reinterpret_cast<const ushort8*>(&lB[(wc * 64 + n * 16 + lr) * 32 + lk]);
#pragma unroll
            for (int m = 0; m < 4; m++)
#pragma unroll
                for (int n = 0; n < 4; n++)
                    acc[m][n] = __builtin_amdgcn_mfma_f32_16x16x32_bf16(
                        __builtin_bit_cast(bf16x8, af[m]), __builtin_bit_cast(bf16x8, bfr[n]),
                        acc[m][n], 0, 0, 0);
            __syncthreads();
        }
        const int crow0 = wr * 64 + (lane >> 4) * 4;
        const int ccol0 = bn0 + wc * 64 + lr;
#pragma unroll
        for (int m = 0; m < 4; m++)
#pragma unroll
            for (int n = 0; n < 4; n++)
#pragma unroll
                for (int rg = 0; rg < 4; rg++) {
                    int row = crow0 + m * 16 + rg;
                    if (row < M)
                        Wtb[(size_t)row * 2048 + ccol0 + n * 16] = f2bf(acc[m][n][rg]);
                }
    }
}

// ============ K3: gemm_T (626 blocks) || k_fill (625 blocks) ============
__global__ __launch_bounds__(256) void k3(
    const float* __restrict__ X, const unsigned short* __restrict__ Wtb,
    float* __restrict__ Tpart,
    const int* __restrict__ ei, const float* __restrict__ ew,
    const float* __restrict__ dinv, const int* __restrict__ rowPtr,
    int* cursor, int* __restrict__ colA, float* __restrict__ valA) {
    __shared__ alignas(16) unsigned short lA[64 * 64];
    __shared__ alignas(16) unsigned short lB[64 * 64];
    const int B = blockIdx.x, t = threadIdx.x;
    if (B >= 626) {                     // ---- k_fill ----
        int e = (B - 626) * 256 + t;
        if (e < N_EDGES) {
            int s = ei[e], d = ei[N_EDGES + e];
            int p = atomicAdd(&cursor[d], 1);
            int j = rowPtr[d] + p;
            colA[j] = s;
            valA[j] = dinv[s] * ew[e] * dinv[d];
        }
        return;
    }
    // ---- gemm_T: Tpart[kp] = X @ Wt^T (64-row tile, N=64, split-K x2) ----
    const int w = t >> 6, lane = t & 63;
    const int kp = B & 1;
    const int bm0 = (B >> 1) * 64;
    const int kbase = kp * 1024;
    const int lr = lane & 15, lkb = (lane >> 4) * 16;

    const int c0 = t, c1 = t + 256;
    const int ar0 = c0 >> 3, ac0 = (c0 & 7) * 8;
    const int ar1 = c1 >> 3, ac1 = (c1 & 7) * 8;
    int gr0 = bm0 + ar0; if (gr0 >= N_NODES) gr0 = N_NODES - 1;
    int gr1 = bm0 + ar1; if (gr1 >= N_NODES) gr1 = N_NODES - 1;
    const float* pA0 = X + (size_t)gr0 * CIN + kbase + ac0;
    const float* pA1 = X + (size_t)gr1 * CIN + kbase + ac1;
    const unsigned short* pB0 = Wtb + ar0 * 2048 + kbase + ac0;
    const unsigned short* pB1 = Wtb + ar1 * 2048 + kbase + ac1;
    char* const LA = (char*)lA;
    char* const LB = (char*)lB;
    char* const wA0 = LA + ((ar0 * 128 + ac0 * 2) ^ ((ar0 & 7) << 4));
    char* const wA1 = LA + ((ar1 * 128 + ac1 * 2) ^ ((ar1 & 7) << 4));
    char* const wB0 = LB + ((ar0 * 128 + ac0 * 2) ^ ((ar0 & 7) << 4));
    char* const wB1 = LB + ((ar1 * 128 + ac1 * 2) ^ ((ar1 & 7) << 4));

    int aoff[4][2], boff[2];
#pragma unroll
    for (int m = 0; m < 4; ++m)
#pragma unroll
        for (int k = 0; k < 2; ++k)
            aoff[m][k] = (((m * 16 + lr) * 128 + k * 64 + lkb) ^ ((lr & 7) << 4));
#pragma unroll
    for (int k = 0; k < 2; ++k)
        boff[k] = (((w * 16 + lr) * 128 + k * 64 + lkb) ^ ((lr & 7) << 4));

    f32x4 acc[4];
#pragma unroll
    for (int m = 0; m < 4; ++m) acc[m] = (f32x4){0.f, 0.f, 0.f, 0.f};

    float4 a00, a01, a10, a11;
    ushort8 bv0, bv1;
    const float4 z4 = make_float4(0.f, 0.f, 0.f, 0.f);

#define STAGE_LOAD(S)                                                              \
    {                                                                              \
        bool v0 = (kbase + ac0 + (S) * 64) < CIN;                                  \
        bool v1 = (kbase + ac1 + (S) * 64) < CIN;                                  \
        const float4* q0 = (const float4*)(v0 ? pA0 + (S) * 64 : (const float*)X); \
        const float4* q1 = (const float4*)(v1 ? pA1 + (S) * 64 : (const float*)X); \
        a00 = q0[0]; a01 = q0[1];                                                  \
        a10 = q1[0]; a11 = q1[1];                                                  \
        if (!v0) { a00 = z4; a01 = z4; }                                           \
        if (!v1) { a10 = z4; a11 = z4; }                                           \
        bv0 = *(const ushort8*)(pB0 + (S) * 64);                                   \
        bv1 = *(const ushort8*)(pB1 + (S) * 64);                                   \
    }

    STAGE_LOAD(0)
    for (int s = 0; s < 16; ++s) {
        __syncthreads();
        *(ushort8*)wA0 = pack8(a00, a01);
        *(ushort8*)wA1 = pack8(a10, a11);
        *(ushort8*)wB0 = bv0;
        *(ushort8*)wB1 = bv1;
        __syncthreads();
        if (s < 15) STAGE_LOAD(s + 1)
#pragma unroll
        for (int k = 0; k < 2; ++k) {
            ushort8 bf = *(const ushort8*)(LB + boff[k]);
#pragma unroll
            for (int m = 0; m < 4; ++m) {
                ushort8 af = *(const ushort8*)(LA + aoff[m][k]);
                acc[m] = __builtin_amdgcn_mfma_f32_16x16x32_bf16(
                    __builtin_bit_cast(bf16x8, af), __builtin_bit_cast(bf16x8, bf),
                    acc[m], 0, 0, 0);
            }
        }
    }
#undef STAGE_LOAD
    float* Tp = Tpart + (size_t)kp * N_NODES * NHP;
    const int col = w * 16 + lr;
    const int rb = bm0 + (lane >> 4) * 4;
#pragma unroll
    for (int m = 0; m < 4; ++m)
#pragma unroll
        for (int rg = 0; rg < 4; ++rg) {
            int row = rb + m * 16 + rg;
            if (row < N_NODES) Tp[(size_t)row * NHP + col] = acc[m][rg];
        }
}

// ================= K4: agg_a with fused split-K reduce =================
__global__ __launch_bounds__(256) void agg_a(
    const float* __restrict__ Tp, const int* __restrict__ rowPtr,
    const int* __restrict__ colA, const float* __restrict__ valA,
    const float* __restrict__ dinv, float* __restrict__ U) {
    const float* __restrict__ T1 = Tp + (size_t)N_NODES * NHP;
    int wid = blockIdx.x * 4 + (threadIdx.x >> 6);
    int lane = threadIdx.x & 63;
    if (wid >= N_NODES) return;
    int d = wid;
    float dv = dinv[d];
    float acc = dv * dv * (Tp[(size_t)d * NHP + lane] + T1[(size_t)d * NHP + lane]);
    int e0 = rowPtr[d], e1 = rowPtr[d + 1];
    int e = e0;
    for (; e + 4 <= e1; e += 4) {
        int s0 = colA[e], s1 = colA[e + 1], s2 = colA[e + 2], s3 = colA[e + 3];
        float w0 = valA[e], w1 = valA[e + 1], w2 = valA[e + 2], w3 = valA[e + 3];
        float t0 = Tp[(size_t)s0 * NHP + lane] + T1[(size_t)s0 * NHP + lane];
        float t1 = Tp[(size_t)s1 * NHP + lane] + T1[(size_t)s1 * NHP + lane];
        float t2 = Tp[(size_t)s2 * NHP + lane] + T1[(size_t)s2 * NHP + lane];
        float t3 = Tp[(size_t)s3 * NHP + lane] + T1[(size_t)s3 * NHP + lane];
        acc += w0 * t0 + w1 * t1 + w2 * t2 + w3 * t3;
    }
    for (; e < e1; ++e) {
        int s = colA[e];
        acc += valA[e] * (Tp[(size_t)s * NHP + lane] + T1[(size_t)s * NHP + lane]);
    }
    U[(size_t)d * NHP + lane] = acc;
}

// ============ K5: agg_b: out = act( A_hat @ U + rowsum*cc + dd ) ============
__global__ __launch_bounds__(256) void agg_b(
    const float* __restrict__ U, const int* __restrict__ rowPtr,
    const int* __restrict__ colA, const float* __restrict__ valA,
    const float* __restrict__ dinv, const float* __restrict__ ccdd,
    float* __restrict__ out) {
    int wid = blockIdx.x * 4 + (threadIdx.x >> 6);
    int lane = threadIdx.x & 63;
    if (wid >= N_NODES) return;
    int d = wid;
    float dv = dinv[d], self = dv * dv;
    float acc = self * U[(size_t)d * NHP + lane];
    float r = self;
    int e0 = rowPtr[d], e1 = rowPtr[d + 1];
    int e = e0;
    for (; e + 4 <= e1; e += 4) {
        int s0 = colA[e], s1 = colA[e + 1], s2 = colA[e + 2], s3 = colA[e + 3];
        float w0 = valA[e], w1 = valA[e + 1], w2 = valA[e + 2], w3 = valA[e + 3];
        float t0 = U[(size_t)s0 * NHP + lane];
        float t1 = U[(size_t)s1 * NHP + lane];
        float t2 = U[(size_t)s2 * NHP + lane];
        float t3 = U[(size_t)s3 * NHP + lane];
        acc += w0 * t0 + w1 * t1 + w2 * t2 + w3 * t3;
        r += w0 + w1 + w2 + w3;
    }
    for (; e < e1; ++e) {
        int s = colA[e];
        float wv = valA[e];
        acc += wv * U[(size_t)s * NHP + lane];
        r += wv;
    }
    if (lane < NH) {
        float v = acc + r * ccdd[lane] + ccdd[NHP + lane];
        if (lane < 2 || lane >= 18)
            v = fmaxf(v, 0.f) + log1pf(expf(-fabsf(v)));
        size_t oidx;
        if (lane == 0)      oidx = (size_t)d;
        else if (lane == 1) oidx = (size_t)N_NODES + d;
        else if (lane < 18) oidx = (size_t)2 * N_NODES + (size_t)d * 16 + (lane - 2);
        else                oidx = (size_t)18 * N_NODES + (size_t)d * 16 + (lane - 18);
        out[oidx] = v;
    }
}

extern "C" void kernel_launch(void* const* d_in, const int* in_sizes, int n_in,
                              void* d_out, int out_size, void* d_ws, size_t ws_size,
                              hipStream_t stream) {
    const float* X   = (const float*)d_in[0];
    const int*   EI  = (const int*)d_in[1];
    const float* EW  = (const float*)d_in[2];
    const float* W1  = (const float*)d_in[3];
    const float* b1  = (const float*)d_in[4];
    const float* W2  = (const float*)d_in[5];
    const float* b2  = (const float*)d_in[6];
    const float* Wmt = (const float*)d_in[7];
    const float* bmt = (const float*)d_in[8];
    const float* Wst = (const float*)d_in[9];
    const float* bst = (const float*)d_in[10];
    const float* Wmz = (const float*)d_in[11];
    const float* bmz = (const float*)d_in[12];
    const float* Wsz = (const float*)d_in[13];
    const float* bsz = (const float*)d_in[14];
    float* out = (float*)d_out;

    char* ws = (char*)d_ws;
    size_t off = 0;
    auto alloc = [&](size_t bytes) -> char* {
        char* p = ws + off;
        off += (bytes + 255) & ~(size_t)255;
        return p;
    };
    float*          V    = (float*)alloc((size_t)NHP * 512 * 4);
    unsigned short* Vb   = (unsigned short*)alloc((size_t)NHP * 512 * 2);
    unsigned short* W1T  = (unsigned short*)alloc((size_t)2048 * 512 * 2);
    unsigned short* Wtb  = (unsigned short*)alloc((size_t)NHP * 2048 * 2);
    float*          ccdd = (float*)alloc(2 * NHP * 4);
    float*          Tp   = (float*)alloc((size_t)2 * N_NODES * NHP * 4);
    float*          U    = (float*)alloc((size_t)N_NODES * NHP * 4);
    float* degsum = (float*)alloc(N_NODES * 4);
    int*   cnt    = (int*)alloc(N_NODES * 4);
    int*   cursor = (int*)alloc(N_NODES * 4);
    float* dinv   = (float*)alloc(N_NODES * 4);
    int*   rowPtr = (int*)alloc((N_NODES + 1) * 4);
    int*   colA   = (int*)alloc(N_EDGES * 4);
    float* valA   = (float*)alloc(N_EDGES * 4);
    if (off > ws_size) return;   // loud failure: d_out stays poisoned

    // zero {degsum, cnt, cursor} in one async memset (contiguous span)
    size_t zspan = (size_t)((char*)(cursor + N_NODES) - (char*)degsum);
    hipMemsetAsync(degsum, 0, zspan, stream);

    k1<<<625 + 128 + 1024, 256, 0, stream>>>(EI, EW, degsum, cnt,
                                             W2, Wmt, Wst, Wmz, Wsz, V, Vb, W1, W1T);
    k2<<<79 + 1 + 16, 256, 0, stream>>>(cnt, degsum, dinv, rowPtr, Vb, W1T, Wtb, V,
                                        b1, b2, bmt, bst, bmz, bsz, Wmt, Wst, Wmz, Wsz, ccdd);
    k3<<<626 + 625, 256, 0, stream>>>(X, Wtb, Tp, EI, EW, dinv, rowPtr, cursor, colA, valA);
    agg_a<<<(N_NODES + 3) / 4, 256, 0, stream>>>(Tp, rowPtr, colA, valA, dinv, U);
    agg_b<<<(N_NODES + 3) / 4, 256, 0, stream>>>(U, rowPtr, colA, valA, dinv, ccdd, out);
}

// Round 14
// 123.452 us; speedup vs baseline: 2.3121x; 1.0077x over previous
//
#include <hip/hip_runtime.h>

#define N_NODES 20000
#define N_EDGES 160000
#define CIN     2000
#define N1      500
#define N2      250
#define NH      34     // heads: 1 + 1 + 16 + 16
#define NHP     64

typedef __attribute__((ext_vector_type(4))) float f32x4;
typedef __attribute__((ext_vector_type(8))) __bf16 bf16x8;
typedef __attribute__((ext_vector_type(8))) unsigned short ushort8;

typedef const __attribute__((address_space(1))) void* as1cv;
typedef __attribute__((address_space(3))) void* as3v;

__device__ __forceinline__ unsigned short f2bf(float f) {
    unsigned int u = __builtin_bit_cast(unsigned int, f);
    u += 0x7FFFu + ((u >> 16) & 1u);   // RNE
    return (unsigned short)(u >> 16);
}

__device__ __forceinline__ ushort8 pack8(float4 a, float4 b) {
    ushort8 r;
    r[0] = f2bf(a.x); r[1] = f2bf(a.y); r[2] = f2bf(a.z); r[3] = f2bf(a.w);
    r[4] = f2bf(b.x); r[5] = f2bf(b.y); r[6] = f2bf(b.z); r[7] = f2bf(b.w);
    return r;
}

// == K1: k_count (625) || V = Wh@W2 (128) || W1 transpose -> bf16 (1024) ==
__global__ __launch_bounds__(256) void k1(
    const int* __restrict__ ei, const float* __restrict__ ew,
    float* degsum, int* cnt,
    const float* __restrict__ W2,
    const float* __restrict__ Wmt, const float* __restrict__ Wst,
    const float* __restrict__ Wmz, const float* __restrict__ Wsz,
    float* __restrict__ V, unsigned short* __restrict__ Vb,
    const float* __restrict__ W1, unsigned short* __restrict__ W1T) {
    __shared__ float tile[32][33];
    const int B = blockIdx.x, t = threadIdx.x;
    if (B < 625) {                      // ---- k_count ----
        int e = B * 256 + t;
        if (e < N_EDGES) {
            int d = ei[N_EDGES + e];
            atomicAdd(&degsum[d], ew[e]);
            atomicAdd(&cnt[d], 1);
        }
        return;
    }
    if (B < 753) {                      // ---- V[o][n] = sum_j Wh[o][j] W2[j][n] ----
        float* wh = &tile[0][0];
        int b = B - 625;
        int o = b >> 1, half = b & 1;
        int n = half * 256 + t;
        if (o >= NH) {
            V[(size_t)o * 512 + n] = 0.f;
            Vb[(size_t)o * 512 + n] = 0;
            return;
        }
        const float* src; int row;
        if (o == 0)      { src = Wmt; row = 0; }
        else if (o == 1) { src = Wst; row = 0; }
        else if (o < 18) { src = Wmz; row = o - 2; }
        else             { src = Wsz; row = o - 18; }
        if (t < N2) wh[t] = src[(size_t)row * N2 + t];
        __syncthreads();
        float acc = 0.f;
        if (n < N1) {
            for (int j = 0; j < N2; ++j) acc += wh[j] * W2[(size_t)j * N1 + n];
        }
        float v = (n < N1) ? acc : 0.f;
        V[(size_t)o * 512 + n] = v;
        Vb[(size_t)o * 512 + n] = f2bf(v);
        return;
    }
    // ---- transpose W1 [500][2000] -> W1T bf16 [2048][512] ----
    int bb = B - 753;
    int jt = bb & 15, nt = bb >> 4;
    int c = t & 31, r = t >> 5;
#pragma unroll
    for (int i = 0; i < 4; ++i) {
        int j = jt * 32 + r + i * 8;
        int n = nt * 32 + c;
        tile[r + i * 8][c] = (j < N1 && n < CIN) ? W1[(size_t)j * CIN + n] : 0.f;
    }
    __syncthreads();
#pragma unroll
    for (int i = 0; i < 4; ++i) {
        int n = nt * 32 + r + i * 8;
        int j = jt * 32 + c;
        W1T[(size_t)n * 512 + j] = f2bf(tile[c][r + i * 8]);
    }
}

// == K2: parallel scan+dinv+zero-cursor (79) || ccdd (1) || MFMA gemm Wt (16) ==
__global__ __launch_bounds__(256) void k2(
    const int* __restrict__ cnt, const float* __restrict__ degsum,
    float* __restrict__ dinv, int* __restrict__ rowPtr, int* __restrict__ cursor,
    const unsigned short* __restrict__ Vb, const unsigned short* __restrict__ W1T,
    unsigned short* __restrict__ Wtb,
    const float* __restrict__ V,
    const float* __restrict__ b1, const float* __restrict__ b2,
    const float* __restrict__ bmt, const float* __restrict__ bst,
    const float* __restrict__ bmz, const float* __restrict__ bsz,
    const float* __restrict__ Wmt, const float* __restrict__ Wst,
    const float* __restrict__ Wmz, const float* __restrict__ Wsz,
    float* __restrict__ ccdd) {
    __shared__ alignas(16) unsigned short lA[128 * 32];
    __shared__ alignas(16) unsigned short lB[128 * 32];
    __shared__ int sdata[256];
    const int B = blockIdx.x, t = threadIdx.x;
    if (B < 79) {                       // ---- scan chunk b: sync-free redundant prefix ----
        const int nbase = B * 256;
        int idx = nbase + t;
        if (idx < N_NODES) cursor[idx] = 0;     // zero cursor for k3's fill
        // base = sum cnt[0..nbase) — coalesced, L2-hot, parallel across blocks
        int s = 0;
        for (int i = t; i < nbase; i += 256) s += cnt[i];
        sdata[t] = s;
        __syncthreads();
        for (int off = 128; off; off >>= 1) {
            if (t < off) sdata[t] += sdata[t + off];
            __syncthreads();
        }
        const int base = sdata[0];
        __syncthreads();
        int v = 0;
        if (idx < N_NODES) {
            v = cnt[idx];
            dinv[idx] = rsqrtf(1.0f + degsum[idx]);
        }
        sdata[t] = v;
        __syncthreads();
        for (int off = 1; off < 256; off <<= 1) {
            int x = (t >= off) ? sdata[t - off] : 0;
            __syncthreads();
            sdata[t] += x;
            __syncthreads();
        }
        if (idx < N_NODES) rowPtr[idx] = base + sdata[t] - v;   // exclusive
        if (B == 78 && t == 255) rowPtr[N_NODES] = base + sdata[255];
        return;
    }
    if (B == 79) {                      // ---- ccdd: cc = V@b1, dd = Wh@b2 + bh ----
        int w = t >> 6, lane = t & 63;
        for (int o = w; o < NH; o += 4) {
            float cc = 0.f;
            for (int n = lane; n < N1; n += 64) cc += V[(size_t)o * 512 + n] * b1[n];
            const float* src; int row; float bias;
            if (o == 0)      { src = Wmt; row = 0;      bias = bmt[0]; }
            else if (o == 1) { src = Wst; row = 0;      bias = bst[0]; }
            else if (o < 18) { src = Wmz; row = o - 2;  bias = bmz[o - 2]; }
            else             { src = Wsz; row = o - 18; bias = bsz[o - 18]; }
            float dd = 0.f;
            for (int j = lane; j < N2; j += 64) dd += src[(size_t)row * N2 + j] * b2[j];
#pragma unroll
            for (int off = 32; off; off >>= 1) {
                cc += __shfl_down(cc, off);
                dd += __shfl_down(dd, off);
            }
            if (lane == 0) { ccdd[o] = cc; ccdd[NHP + o] = dd + bias; }
        }
        if (t >= NH && t < NHP) { ccdd[t] = 0.f; ccdd[NHP + t] = 0.f; }
        return;
    }
    // ---- MFMA gemm: Wtb[64][2048] = Vb[64][512] @ W1T[2048][512]^T ----
    {
        const int w = t >> 6, lane = t & 63;
        const int bn0 = (B - 80) * 128;
        const int M = 64;
        const int wr = w >> 1, wc = w & 1;
        const int lr = lane & 15, lk = (lane >> 4) * 8;
        f32x4 acc[4][4];
#pragma unroll
        for (int i = 0; i < 4; i++)
#pragma unroll
            for (int j = 0; j < 4; j++) acc[i][j] = (f32x4){0.f, 0.f, 0.f, 0.f};
        for (int kt = 0; kt < 16; ++kt) {
            const int kb = kt * 32;
#pragma unroll
            for (int i = 0; i < 2; i++) {
                int c0 = i * 256 + w * 64;
                int c  = c0 + lane;
                int rr = c >> 2, kg = c & 3;
                int grow = rr < M ? rr : M - 1;
                const unsigned short* gp = Vb + (size_t)grow * 512 + kb + kg * 8;
                __builtin_amdgcn_global_load_lds((as1cv)gp, (as3v)(lA + (size_t)c0 * 8), 16, 0, 0);
            }
#pragma unroll
            for (int i = 0; i < 2; i++) {
                int c0 = i * 256 + w * 64;
                int c  = c0 + lane;
                int rr = c >> 2, kg = c & 3;
                const unsigned short* gp = W1T + (size_t)(bn0 + rr) * 512 + kb + kg * 8;
                __builtin_amdgcn_global_load_lds((as1cv)gp, (as3v)(lB + (size_t)c0 * 8), 16, 0, 0);
            }
            __syncthreads();
            ushort8 af[4], bfr[4];
#pragma unroll
            for (int m = 0; m < 4; m++)
                af[m] = *reinterpret_cast<const ushort8*>(&lA[(wr * 64 + m * 16 + lr) * 32 + lk]);
#pragma unroll
            for (int n = 0; n < 4; n++)
                bfr[n] = *reinterpret_cast<const ushort8*>(&lB[(wc * 64 + n * 16 + lr) * 32 + lk]);
#pragma unroll
            for (int m = 0; m < 4; m++)
#pragma unroll
                for (int n = 0; n < 4; n++)
                    acc[m][n] = __builtin_amdgcn_mfma_f32_16x16x32_bf16(
                        __builtin_bit_cast(bf16x8, af[m]), __builtin_bit_cast(bf16x8, bfr[n]),
                        acc[m][n], 0, 0, 0);
            __syncthreads();
        }
        const int crow0 = wr * 64 + (lane >> 4) * 4;
        const int ccol0 = bn0 + wc * 64 + lr;
#pragma unroll
        for (int m = 0; m < 4; m++)
#pragma unroll
            for (int n = 0; n < 4; n++)
#pragma unroll
                for (int rg = 0; rg < 4; rg++) {
                    int row = crow0 + m * 16 + rg;
                    if (row < M)
                        Wtb[(size_t)row * 2048 + ccol0 + n * 16] = f2bf(acc[m][n][rg]);
                }
    }
}

// ============ K3: gemm_T (626 blocks, 2-deep prefetch) || k_fill (625) ============
__global__ __launch_bounds__(256) void k3(
    const float* __restrict__ X, const unsigned short* __restrict__ Wtb,
    float* __restrict__ Tpart,
    const int* __restrict__ ei, const float* __restrict__ ew,
    const float* __restrict__ dinv, const int* __restrict__ rowPtr,
    int* cursor, int* __restrict__ colA, float* __restrict__ valA) {
    __shared__ alignas(16) unsigned short lA[64 * 64];
    __shared__ alignas(16) unsigned short lB[64 * 64];
    const int B = blockIdx.x, t = threadIdx.x;
    if (B >= 626) {                     // ---- k_fill ----
        int e = (B - 626) * 256 + t;
        if (e < N_EDGES) {
            int s = ei[e], d = ei[N_EDGES + e];
            int p = atomicAdd(&cursor[d], 1);
            int j = rowPtr[d] + p;
            colA[j] = s;
            valA[j] = dinv[s] * ew[e] * dinv[d];
        }
        return;
    }
    // ---- gemm_T: Tpart[kp] = X @ Wt^T (64-row tile, N=64, split-K x2) ----
    const int w = t >> 6, lane = t & 63;
    const int kp = B & 1;
    const int bm0 = (B >> 1) * 64;
    const int kbase = kp * 1024;
    const int lr = lane & 15, lkb = (lane >> 4) * 16;

    const int c0 = t, c1 = t + 256;
    const int ar0 = c0 >> 3, ac0 = (c0 & 7) * 8;
    const int ar1 = c1 >> 3, ac1 = (c1 & 7) * 8;
    int gr0 = bm0 + ar0; if (gr0 >= N_NODES) gr0 = N_NODES - 1;
    int gr1 = bm0 + ar1; if (gr1 >= N_NODES) gr1 = N_NODES - 1;
    const float* pA0 = X + (size_t)gr0 * CIN + kbase + ac0;
    const float* pA1 = X + (size_t)gr1 * CIN + kbase + ac1;
    const unsigned short* pB0 = Wtb + ar0 * 2048 + kbase + ac0;
    const unsigned short* pB1 = Wtb + ar1 * 2048 + kbase + ac1;
    char* const LA = (char*)lA;
    char* const LB = (char*)lB;
    char* const wA0 = LA + ((ar0 * 128 + ac0 * 2) ^ ((ar0 & 7) << 4));
    char* const wA1 = LA + ((ar1 * 128 + ac1 * 2) ^ ((ar1 & 7) << 4));
    char* const wB0 = LB + ((ar0 * 128 + ac0 * 2) ^ ((ar0 & 7) << 4));
    char* const wB1 = LB + ((ar1 * 128 + ac1 * 2) ^ ((ar1 & 7) << 4));

    int aoff[4][2], boff[2];
#pragma unroll
    for (int m = 0; m < 4; ++m)
#pragma unroll
        for (int k = 0; k < 2; ++k)
            aoff[m][k] = (((m * 16 + lr) * 128 + k * 64 + lkb) ^ ((lr & 7) << 4));
#pragma unroll
    for (int k = 0; k < 2; ++k)
        boff[k] = (((w * 16 + lr) * 128 + k * 64 + lkb) ^ ((lr & 7) << 4));

    f32x4 acc[4];
#pragma unroll
    for (int m = 0; m < 4; ++m) acc[m] = (f32x4){0.f, 0.f, 0.f, 0.f};

    // two named register sets (static indexing only — rule: no runtime-indexed reg arrays)
    float4 a00A, a01A, a10A, a11A; ushort8 bv0A, bv1A;
    float4 a00B, a01B, a10B, a11B; ushort8 bv0B, bv1B;
    const float4 z4 = make_float4(0.f, 0.f, 0.f, 0.f);

#define STAGE_LOAD(S, a00_, a01_, a10_, a11_, bv0_, bv1_)                          \
    {                                                                              \
        bool v0 = (kbase + ac0 + (S) * 64) < CIN;                                  \
        bool v1 = (kbase + ac1 + (S) * 64) < CIN;                                  \
        const float4* q0 = (const float4*)(v0 ? pA0 + (S) * 64 : (const float*)X); \
        const float4* q1 = (const float4*)(v1 ? pA1 + (S) * 64 : (const float*)X); \
        a00_ = q0[0]; a01_ = q0[1];                                                \
        a10_ = q1[0]; a11_ = q1[1];                                                \
        if (!v0) { a00_ = z4; a01_ = z4; }                                         \
        if (!v1) { a10_ = z4; a11_ = z4; }                                         \
        bv0_ = *(const ushort8*)(pB0 + (S) * 64);                                  \
        bv1_ = *(const ushort8*)(pB1 + (S) * 64);                                  \
    }

    auto compute = [&]() {
#pragma unroll
        for (int k = 0; k < 2; ++k) {
            ushort8 bf = *(const ushort8*)(LB + boff[k]);
#pragma unroll
            for (int m = 0; m < 4; ++m) {
                ushort8 af = *(const ushort8*)(LA + aoff[m][k]);
                acc[m] = __builtin_amdgcn_mfma_f32_16x16x32_bf16(
                    __builtin_bit_cast(bf16x8, af), __builtin_bit_cast(bf16x8, bf),
                    acc[m], 0, 0, 0);
            }
        }
    };

    STAGE_LOAD(0, a00A, a01A, a10A, a11A, bv0A, bv1A)
    STAGE_LOAD(1, a00B, a01B, a10B, a11B, bv0B, bv1B)
    for (int s2 = 0; s2 < 8; ++s2) {
        const int s = 2 * s2;
        // even step: data in set A; prefetch s+2 into A
        __syncthreads();
        *(ushort8*)wA0 = pack8(a00A, a01A);
        *(ushort8*)wA1 = pack8(a10A, a11A);
        *(ushort8*)wB0 = bv0A;
        *(ushort8*)wB1 = bv1A;
        __syncthreads();
        if (s + 2 < 16) STAGE_LOAD(s + 2, a00A, a01A, a10A, a11A, bv0A, bv1A)
        compute();
        // odd step: data in set B; prefetch s+3 into B
        __syncthreads();
        *(ushort8*)wA0 = pack8(a00B, a01B);
        *(ushort8*)wA1 = pack8(a10B, a11B);
        *(ushort8*)wB0 = bv0B;
        *(ushort8*)wB1 = bv1B;
        __syncthreads();
        if (s + 3 < 16) STAGE_LOAD(s + 3, a00B, a01B, a10B, a11B, bv0B, bv1B)
        compute();
    }
#undef STAGE_LOAD
    float* Tp = Tpart + (size_t)kp * N_NODES * NHP;
    const int col = w * 16 + lr;
    const int rb = bm0 + (lane >> 4) * 4;
#pragma unroll
    for (int m = 0; m < 4; ++m)
#pragma unroll
        for (int rg = 0; rg < 4; ++rg) {
            int row = rb + m * 16 + rg;
            if (row < N_NODES) Tp[(size_t)row * NHP + col] = acc[m][rg];
        }
}

// ====== K4: agg_a: U = A_hat @ (Tp0+Tp1), 8-deep gather unroll ======
__global__ __launch_bounds__(256) void agg_a(
    const float* __restrict__ Tp, const int* __restrict__ rowPtr,
    const int* __restrict__ colA, const float* __restrict__ valA,
    const float* __restrict__ dinv, float* __restrict__ U) {
    const float* __restrict__ T1 = Tp + (size_t)N_NODES * NHP;
    int wid = blockIdx.x * 4 + (threadIdx.x >> 6);
    int lane = threadIdx.x & 63;
    if (wid >= N_NODES) return;
    int d = wid;
    float dv = dinv[d];
    float acc = dv * dv * (Tp[(size_t)d * NHP + lane] + T1[(size_t)d * NHP + lane]);
    int e0 = rowPtr[d], e1 = rowPtr[d + 1];
    int e = e0;
    for (; e + 8 <= e1; e += 8) {
        int   s0 = colA[e],     s1 = colA[e + 1], s2 = colA[e + 2], s3 = colA[e + 3];
        int   s4 = colA[e + 4], s5 = colA[e + 5], s6 = colA[e + 6], s7 = colA[e + 7];
        float w0 = valA[e],     w1 = valA[e + 1], w2 = valA[e + 2], w3 = valA[e + 3];
        float w4 = valA[e + 4], w5 = valA[e + 5], w6 = valA[e + 6], w7 = valA[e + 7];
        float t0 = Tp[(size_t)s0 * NHP + lane] + T1[(size_t)s0 * NHP + lane];
        float t1 = Tp[(size_t)s1 * NHP + lane] + T1[(size_t)s1 * NHP + lane];
        float t2 = Tp[(size_t)s2 * NHP + lane] + T1[(size_t)s2 * NHP + lane];
        float t3 = Tp[(size_t)s3 * NHP + lane] + T1[(size_t)s3 * NHP + lane];
        float t4 = Tp[(size_t)s4 * NHP + lane] + T1[(size_t)s4 * NHP + lane];
        float t5 = Tp[(size_t)s5 * NHP + lane] + T1[(size_t)s5 * NHP + lane];
        float t6 = Tp[(size_t)s6 * NHP + lane] + T1[(size_t)s6 * NHP + lane];
        float t7 = Tp[(size_t)s7 * NHP + lane] + T1[(size_t)s7 * NHP + lane];
        acc += w0 * t0 + w1 * t1 + w2 * t2 + w3 * t3
             + w4 * t4 + w5 * t5 + w6 * t6 + w7 * t7;
    }
    for (; e + 4 <= e1; e += 4) {
        int s0 = colA[e], s1 = colA[e + 1], s2 = colA[e + 2], s3 = colA[e + 3];
        float w0 = valA[e], w1 = valA[e + 1], w2 = valA[e + 2], w3 = valA[e + 3];
        float t0 = Tp[(size_t)s0 * NHP + lane] + T1[(size_t)s0 * NHP + lane];
        float t1 = Tp[(size_t)s1 * NHP + lane] + T1[(size_t)s1 * NHP + lane];
        float t2 = Tp[(size_t)s2 * NHP + lane] + T1[(size_t)s2 * NHP + lane];
        float t3 = Tp[(size_t)s3 * NHP + lane] + T1[(size_t)s3 * NHP + lane];
        acc += w0 * t0 + w1 * t1 + w2 * t2 + w3 * t3;
    }
    for (; e < e1; ++e) {
        int s = colA[e];
        acc += valA[e] * (Tp[(size_t)s * NHP + lane] + T1[(size_t)s * NHP + lane]);
    }
    U[(size_t)d * NHP + lane] = acc;
}

// ====== K5: agg_b: out = act( A_hat @ U + rowsum*cc + dd ), 8-deep unroll ======
__global__ __launch_bounds__(256) void agg_b(
    const float* __restrict__ U, const int* __restrict__ rowPtr,
    const int* __restrict__ colA, const float* __restrict__ valA,
    const float* __restrict__ dinv, const float* __restrict__ ccdd,
    float* __restrict__ out) {
    int wid = blockIdx.x * 4 + (threadIdx.x >> 6);
    int lane = threadIdx.x & 63;
    if (wid >= N_NODES) return;
    int d = wid;
    float dv = dinv[d], self = dv * dv;
    float acc = self * U[(size_t)d * NHP + lane];
    float r = self;
    int e0 = rowPtr[d], e1 = rowPtr[d + 1];
    int e = e0;
    for (; e + 8 <= e1; e += 8) {
        int   s0 = colA[e],     s1 = colA[e + 1], s2 = colA[e + 2], s3 = colA[e + 3];
        int   s4 = colA[e + 4], s5 = colA[e + 5], s6 = colA[e + 6], s7 = colA[e + 7];
        float w0 = valA[e],     w1 = valA[e + 1], w2 = valA[e + 2], w3 = valA[e + 3];
        float w4 = valA[e + 4], w5 = valA[e + 5], w6 = valA[e + 6], w7 = valA[e + 7];
        float t0 = U[(size_t)s0 * NHP + lane], t1 = U[(size_t)s1 * NHP + lane];
        float t2 = U[(size_t)s2 * NHP + lane], t3 = U[(size_t)s3 * NHP + lane];
        float t4 = U[(size_t)s4 * NHP + lane], t5 = U[(size_t)s5 * NHP + lane];
        float t6 = U[(size_t)s6 * NHP + lane], t7 = U[(size_t)s7 * NHP + lane];
        acc += w0 * t0 + w1 * t1 + w2 * t2 + w3 * t3
             + w4 * t4 + w5 * t5 + w6 * t6 + w7 * t7;
        r += w0 + w1 + w2 + w3 + w4 + w5 + w6 + w7;
    }
    for (; e + 4 <= e1; e += 4) {
        int s0 = colA[e], s1 = colA[e + 1], s2 = colA[e + 2], s3 = colA[e + 3];
        float w0 = valA[e], w1 = valA[e + 1], w2 = valA[e + 2], w3 = valA[e + 3];
        float t0 = U[(size_t)s0 * NHP + lane], t1 = U[(size_t)s1 * NHP + lane];
        float t2 = U[(size_t)s2 * NHP + lane], t3 = U[(size_t)s3 * NHP + lane];
        acc += w0 * t0 + w1 * t1 + w2 * t2 + w3 * t3;
        r += w0 + w1 + w2 + w3;
    }
    for (; e < e1; ++e) {
        int s = colA[e];
        float wv = valA[e];
        acc += wv * U[(size_t)s * NHP + lane];
        r += wv;
    }
    if (lane < NH) {
        float v = acc + r * ccdd[lane] + ccdd[NHP + lane];
        if (lane < 2 || lane >= 18)
            v = fmaxf(v, 0.f) + log1pf(expf(-fabsf(v)));
        size_t oidx;
        if (lane == 0)      oidx = (size_t)d;
        else if (lane == 1) oidx = (size_t)N_NODES + d;
        else if (lane < 18) oidx = (size_t)2 * N_NODES + (size_t)d * 16 + (lane - 2);
        else                oidx = (size_t)18 * N_NODES + (size_t)d * 16 + (lane - 18);
        out[oidx] = v;
    }
}

extern "C" void kernel_launch(void* const* d_in, const int* in_sizes, int n_in,
                              void* d_out, int out_size, void* d_ws, size_t ws_size,
                              hipStream_t stream) {
    const float* X   = (const float*)d_in[0];
    const int*   EI  = (const int*)d_in[1];
    const float* EW  = (const float*)d_in[2];
    const float* W1  = (const float*)d_in[3];
    const float* b1  = (const float*)d_in[4];
    const float* W2  = (const float*)d_in[5];
    const float* b2  = (const float*)d_in[6];
    const float* Wmt = (const float*)d_in[7];
    const float* bmt = (const float*)d_in[8];
    const float* Wst = (const float*)d_in[9];
    const float* bst = (const float*)d_in[10];
    const float* Wmz = (const float*)d_in[11];
    const float* bmz = (const float*)d_in[12];
    const float* Wsz = (const float*)d_in[13];
    const float* bsz = (const float*)d_in[14];
    float* out = (float*)d_out;

    char* ws = (char*)d_ws;
    size_t off = 0;
    auto alloc = [&](size_t bytes) -> char* {
        char* p = ws + off;
        off += (bytes + 255) & ~(size_t)255;
        return p;
    };
    float*          V    = (float*)alloc((size_t)NHP * 512 * 4);
    unsigned short* Vb   = (unsigned short*)alloc((size_t)NHP * 512 * 2);
    unsigned short* W1T  = (unsigned short*)alloc((size_t)2048 * 512 * 2);
    unsigned short* Wtb  = (unsigned short*)alloc((size_t)NHP * 2048 * 2);
    float*          ccdd = (float*)alloc(2 * NHP * 4);
    float*          Tp   = (float*)alloc((size_t)2 * N_NODES * NHP * 4);
    float*          U    = (float*)alloc((size_t)N_NODES * NHP * 4);
    float* degsum = (float*)alloc(N_NODES * 4);
    int*   cnt    = (int*)alloc(N_NODES * 4);
    int*   cursor = (int*)alloc(N_NODES * 4);
    float* dinv   = (float*)alloc(N_NODES * 4);
    int*   rowPtr = (int*)alloc((N_NODES + 1) * 4);
    int*   colA   = (int*)alloc(N_EDGES * 4);
    float* valA   = (float*)alloc(N_EDGES * 4);
    if (off > ws_size) return;   // loud failure: d_out stays poisoned

    // zero {degsum, cnt} only; cursor is zeroed inside k2 (used first in k3)
    size_t zspan = (size_t)((char*)(cnt + N_NODES) - (char*)degsum);
    hipMemsetAsync(degsum, 0, zspan, stream);

    k1<<<625 + 128 + 1024, 256, 0, stream>>>(EI, EW, degsum, cnt,
                                             W2, Wmt, Wst, Wmz, Wsz, V, Vb, W1, W1T);
    k2<<<79 + 1 + 16, 256, 0, stream>>>(cnt, degsum, dinv, rowPtr, cursor,
                                        Vb, W1T, Wtb, V,
                                        b1, b2, bmt, bst, bmz, bsz, Wmt, Wst, Wmz, Wsz, ccdd);
    k3<<<626 + 625, 256, 0, stream>>>(X, Wtb, Tp, EI, EW, dinv, rowPtr, cursor, colA, valA);
    agg_a<<<(N_NODES + 3) / 4, 256, 0, stream>>>(Tp, rowPtr, colA, valA, dinv, U);
    agg_b<<<(N_NODES + 3) / 4, 256, 0, stream>>>(U, rowPtr, colA, valA, dinv, ccdd, out);
}